// Round 2
// baseline (1570.507 us; speedup 1.0000x reference)
//
#include <hip/hip_runtime.h>
#include <hip/hip_bf16.h>
#include <math.h>

#define Nn 8192
#define Dd 256
#define Uu 128
#define BI 16
#define TJ 256
#define NEG_MIN -3.4028235e38f

typedef __hip_bfloat16 bf16;

__device__ __forceinline__ float waveSum(float v){
  #pragma unroll
  for (int off = 32; off >= 1; off >>= 1) v += __shfl_xor(v, off);
  return v;
}
__device__ __forceinline__ float waveMax(float v){
  #pragma unroll
  for (int off = 32; off >= 1; off >>= 1) v = fmaxf(v, __shfl_xor(v, off));
  return v;
}

__device__ __forceinline__ float blockSum256(float v, volatile float* s4){
  v = waveSum(v);
  __syncthreads();
  if ((threadIdx.x & 63) == 0) s4[threadIdx.x >> 6] = v;
  __syncthreads();
  return s4[0] + s4[1] + s4[2] + s4[3];
}

// Decide whether float inputs are fp32 or bf16 by decoding `kernel` as bf16:
// true bf16 weights are all |v| < ~1; fp32 bits misread as bf16 give random
// exponents -> thousands of |v|>1000. Writes flag (1 = fp32 mode) to ws.
__global__ __launch_bounds__(256) void k_sniff(const unsigned short* __restrict__ buf,
                                               int n, int* __restrict__ flag){
  __shared__ int cnt;
  if (threadIdx.x == 0) cnt = 0;
  __syncthreads();
  int local = 0;
  for (int i = threadIdx.x; i < n; i += 256){
    unsigned int bits = ((unsigned int)buf[i]) << 16;
    float v = __uint_as_float(bits);
    if (!(fabsf(v) <= 1000.f)) local++;   // catches big and NaN
  }
  atomicAdd(&cnt, local);
  __syncthreads();
  if (threadIdx.x == 0) *flag = (cnt > 100) ? 1 : 0;
}

template <bool FP32>
__device__ __forceinline__ float ldin(const void* p, size_t i){
  if (FP32) return ((const float*)p)[i];
  return __bfloat162float(((const bf16*)p)[i]);
}

// x = expmap0(features @ kernel), also xT (transposed) and x2 = ||x||^2 per row
template <bool FP32>
__global__ __launch_bounds__(128) void k_prep(const int* __restrict__ flag,
                                              const void* __restrict__ feat,
                                              const void* __restrict__ kern,
                                              float* __restrict__ x,
                                              float* __restrict__ xT,
                                              float* __restrict__ x2){
  if ((*flag != 0) != FP32) return;
  const int t = threadIdx.x;          // 0..127 == u
  const int n0 = blockIdx.x * 4;
  __shared__ float fS[4][Dd];
  __shared__ float red[2][4];
  for (int idx = t; idx < 4 * Dd; idx += 128)
    fS[idx >> 8][idx & (Dd - 1)] =
        ldin<FP32>(feat, (size_t)(n0 + (idx >> 8)) * Dd + (idx & (Dd - 1)));
  __syncthreads();
  float zz[4] = {0.f, 0.f, 0.f, 0.f};
  for (int d = 0; d < Dd; ++d){
    float kv = ldin<FP32>(kern, (size_t)d * Uu + t);
    #pragma unroll
    for (int r = 0; r < 4; ++r) zz[r] = fmaf(fS[r][d], kv, zz[r]);
  }
  #pragma unroll
  for (int r = 0; r < 4; ++r){
    float v = waveSum(zz[r] * zz[r]);
    if ((t & 63) == 0) red[t >> 6][r] = v;
  }
  __syncthreads();
  #pragma unroll
  for (int r = 0; r < 4; ++r){
    float ns  = red[0][r] + red[1][r];
    float nrm = fmaxf(sqrtf(ns), 1e-15f);
    float th  = tanhf(nrm);
    float scl = th / nrm;
    float xv  = zz[r] * scl;
    x[(size_t)(n0 + r) * Uu + t] = xv;
    xT[(size_t)t * Nn + (n0 + r)] = xv;
    if (t == 0) x2[n0 + r] = th * th;
  }
}

// b = expmap0(bias); bb[0..127] = b, bb[128] = ||b||^2
template <bool FP32>
__global__ __launch_bounds__(128) void k_bias(const int* __restrict__ flag,
                                              const void* __restrict__ bias,
                                              float* __restrict__ bb){
  if ((*flag != 0) != FP32) return;
  const int t = threadIdx.x;
  __shared__ float red[2];
  float bv = ldin<FP32>(bias, t);
  float v = waveSum(bv * bv);
  if ((t & 63) == 0) red[t >> 6] = v;
  __syncthreads();
  float n2  = red[0] + red[1];
  float nrm = fmaxf(sqrtf(n2), 1e-15f);
  float th  = tanhf(nrm);
  bb[t] = bv * th / nrm;
  if (t == 0) bb[Uu] = th * th;
}

// fused: pairwise hyperbolic dist -> masked online softmax -> att@x -> mobius epilogue
__global__ __launch_bounds__(256) void k_attn(const int* __restrict__ flag,
                                              const int* __restrict__ adj,
                                              const float* __restrict__ x,
                                              const float* __restrict__ xT,
                                              const float* __restrict__ x2g,
                                              const float* __restrict__ bvec,
                                              void* __restrict__ outv){
  const int t    = threadIdx.x;
  const int lane = t & 63;
  const int wid  = t >> 6;
  const int i0   = blockIdx.x * BI;
  const bool fp32out = (*flag != 0);

  __shared__ float xiS[BI * Uu];        // 8 KB   x rows of this block
  __shared__ float accS[2 * BI * Uu];   // 16 KB  [half][r][u] partial P.V
  __shared__ float pS[BI * TJ];         // 16 KB  softmax weights this tile
  __shared__ float bS[Uu + 1];
  __shared__ float x2iS[BI], BvS[BI], mS[BI], lS[BI], alphaS[BI], mrowS[BI];
  __shared__ float wred[4][BI];
  __shared__ float sred[4];

  for (int idx = t; idx < BI * Uu; idx += 256) xiS[idx] = x[(size_t)i0 * Uu + idx];
  for (int idx = t; idx < 2 * BI * Uu; idx += 256) accS[idx] = 0.f;
  if (t < BI){
    float v = x2g[i0 + t];
    x2iS[t] = v; BvS[t] = 1.f - v; mS[t] = -INFINITY; lS[t] = 0.f;
  }
  if (t < Uu + 1) bS[t] = bvec[t];
  __syncthreads();

  for (int j0 = 0; j0 < Nn; j0 += TJ){
    const int j = j0 + t;
    const float x2j = x2g[j];
    float sc[BI];
    #pragma unroll
    for (int r = 0; r < BI; ++r) sc[r] = 0.f;

    // dots: sc[r] = x_i[r] . x_j
    for (int uq = 0; uq < Uu / 4; ++uq){
      const int u = uq * 4;
      float a0 = xT[(size_t)(u + 0) * Nn + j];
      float a1 = xT[(size_t)(u + 1) * Nn + j];
      float a2 = xT[(size_t)(u + 2) * Nn + j];
      float a3 = xT[(size_t)(u + 3) * Nn + j];
      #pragma unroll
      for (int r = 0; r < BI; ++r){
        const float4 w = *(const float4*)(&xiS[r * Uu + u]);
        sc[r] = fmaf(w.x, a0, fmaf(w.y, a1, fmaf(w.z, a2, fmaf(w.w, a3, sc[r]))));
      }
    }

    // closed-form Poincare distance + adjacency mask
    #pragma unroll
    for (int r = 0; r < BI; ++r){
      float xy  = sc[r];
      float x2i = x2iS[r];
      float Aa  = 1.f - 2.f * xy + x2j;
      float Bb  = BvS[r];
      float num = Aa * Aa * x2i - 2.f * Aa * Bb * xy + Bb * Bb * x2j;
      float den = 1.f - 2.f * xy + x2i * x2j;
      float mn  = sqrtf(fmaxf(num, 0.f)) / fmaxf(den, 1e-15f);
      mn = fminf(mn, 1.f - 1e-7f);
      float dist = __logf((1.f + mn) / (1.f - mn));   // 2*artanh(mn)
      int av = adj[(size_t)(i0 + r) * Nn + j];
      sc[r] = (av != 0 && dist != 0.f) ? dist : NEG_MIN;
    }

    // tile max per row
    #pragma unroll
    for (int r = 0; r < BI; ++r){
      float v = waveMax(sc[r]);
      if (lane == 0) wred[wid][r] = v;
    }
    __syncthreads();
    if (t < BI){
      float mt  = fmaxf(fmaxf(wred[0][t], wred[1][t]), fmaxf(wred[2][t], wred[3][t]));
      float mo  = mS[t];
      float mnw = fmaxf(mo, mt);
      alphaS[t] = __expf(mo - mnw);
      mS[t] = mnw; mrowS[t] = mnw;
    }
    __syncthreads();

    // p = exp(s - m), tile sum per row
    #pragma unroll
    for (int r = 0; r < BI; ++r){
      float p = __expf(sc[r] - mrowS[r]);
      pS[r * TJ + t] = p;
      float v = waveSum(p);
      if (lane == 0) wred[wid][r] = v;
    }
    __syncthreads();
    if (t < BI) lS[t] = lS[t] * alphaS[t] + (wred[0][t] + wred[1][t] + wred[2][t] + wred[3][t]);
    for (int idx = t; idx < 2 * BI * Uu; idx += 256){
      int r = (idx >> 7) & (BI - 1);
      accS[idx] *= alphaS[r];
    }
    __syncthreads();

    // acc[r][u] += sum_jj p[r][jj] * x[j0+jj][u]   (threads remapped to (u,half))
    {
      const int u = t & (Uu - 1);
      const int h = t >> 7;
      float part[BI];
      #pragma unroll
      for (int r = 0; r < BI; ++r) part[r] = 0.f;
      const float* xp = x + (size_t)(j0 + h * 128) * Uu + u;
      const float* pb = pS + h * 128;
      for (int jq = 0; jq < 32; ++jq){
        const int jj = jq * 4;
        float xv0 = xp[(size_t)(jj + 0) * Uu];
        float xv1 = xp[(size_t)(jj + 1) * Uu];
        float xv2 = xp[(size_t)(jj + 2) * Uu];
        float xv3 = xp[(size_t)(jj + 3) * Uu];
        #pragma unroll
        for (int r = 0; r < BI; ++r){
          const float4 p4 = *(const float4*)(&pb[r * TJ + jj]);
          part[r] = fmaf(p4.x, xv0, fmaf(p4.y, xv1, fmaf(p4.z, xv2, fmaf(p4.w, xv3, part[r]))));
        }
      }
      #pragma unroll
      for (int r = 0; r < BI; ++r) accS[(h * BI + r) * Uu + u] += part[r];
    }
    __syncthreads();
  }

  // merge halves
  for (int idx = t; idx < BI * Uu; idx += 256) accS[idx] += accS[BI * Uu + idx];
  __syncthreads();

  // epilogue: mobius matvec rescale + mobius bias add
  const float b2 = bS[Uu];
  for (int r = 0; r < BI; ++r){
    float mx = 0.f;
    if (t < Uu) mx = accS[r * Uu + t] / lS[r];
    float mx2  = blockSum256(mx * mx, sred);
    float mx_n = fmaxf(sqrtf(mx2), 1e-15f);
    float x_n  = fmaxf(sqrtf(x2iS[r]), 1e-15f);
    float xcl  = fminf(x_n, 1.f - 1e-7f);
    float art  = 0.5f * logf((1.f + xcl) / (1.f - xcl));
    float th   = tanhf(mx_n / x_n * art);
    float o = 0.f, bu = 0.f;
    if (t < Uu){ o = th * mx / mx_n; bu = bS[t]; }
    float o2 = blockSum256(o * o, sred);
    float ob = blockSum256(o * bu, sred);
    if (t < Uu){
      float numv = (1.f + 2.f * ob + b2) * o + (1.f - o2) * bu;
      float denv = 1.f + 2.f * ob + o2 * b2;
      float val  = numv / fmaxf(denv, 1e-15f);
      if (fp32out) ((float*)outv)[(size_t)(i0 + r) * Uu + t] = val;
      else         ((bf16*)outv)[(size_t)(i0 + r) * Uu + t] = __float2bfloat16(val);
    }
  }
}

extern "C" void kernel_launch(void* const* d_in, const int* in_sizes, int n_in,
                              void* d_out, int out_size, void* d_ws, size_t ws_size,
                              hipStream_t stream){
  (void)in_sizes; (void)n_in; (void)out_size; (void)ws_size;
  const void* feat = d_in[0];
  const int*  adj  = (const int*)d_in[1];
  const void* kern = d_in[2];
  const void* bias = d_in[3];

  float* x   = (float*)d_ws;                // [N, U]
  float* xT  = x  + (size_t)Nn * Uu;        // [U, N]
  float* x2  = xT + (size_t)Nn * Uu;        // [N]
  float* bb  = x2 + Nn;                     // [U+1]
  int*   flg = (int*)(bb + Uu + 1);

  k_sniff<<<1, 256, 0, stream>>>((const unsigned short*)kern, Dd * Uu, flg);
  k_prep<false><<<Nn / 4, 128, 0, stream>>>(flg, feat, kern, x, xT, x2);
  k_prep<true ><<<Nn / 4, 128, 0, stream>>>(flg, feat, kern, x, xT, x2);
  k_bias<false><<<1, 128, 0, stream>>>(flg, bias, bb);
  k_bias<true ><<<1, 128, 0, stream>>>(flg, bias, bb);
  k_attn<<<Nn / BI, 256, 0, stream>>>(flg, adj, x, xT, x2, bb, d_out);
}

// Round 3
// 923.853 us; speedup vs baseline: 1.7000x; 1.7000x over previous
//
#include <hip/hip_runtime.h>
#include <hip/hip_bf16.h>
#include <math.h>

#define Nn 8192
#define Dd 256
#define Uu 128
#define MI 16
#define NJ 64
#define PSTR 72
#define NEG_MIN -3.4028235e38f

typedef __attribute__((ext_vector_type(4))) float f32x4;
typedef __attribute__((ext_vector_type(8))) short s16x8;

#define MFMA16(a, b, c) __builtin_amdgcn_mfma_f32_16x16x32_bf16((a), (b), (c), 0, 0, 0)

__device__ __forceinline__ short f2bf(float f){
  unsigned int u = __float_as_uint(f);
  u += 0x7fffu + ((u >> 16) & 1u);           // RNE to bf16
  return (short)(u >> 16);
}

__device__ __forceinline__ float waveSum(float v){
  #pragma unroll
  for (int off = 32; off >= 1; off >>= 1) v += __shfl_xor(v, off);
  return v;
}

// x = expmap0(features @ kernel)  ->  x_hi (bf16 [N][U]), xT_hi (bf16 [U][N]), x2 (f32, = tanh(|z|)^2)
__global__ __launch_bounds__(128) void k_prep(const float* __restrict__ feat,
                                              const float* __restrict__ kern,
                                              short* __restrict__ x_hi,
                                              short* __restrict__ xT_hi,
                                              float* __restrict__ x2){
  const int t = threadIdx.x;                  // == u
  const int n0 = blockIdx.x * 4;
  __shared__ float fS[4][Dd];
  __shared__ float red[2][4];
  for (int idx = t; idx < 4 * Dd; idx += 128)
    fS[idx >> 8][idx & 255] = feat[(size_t)(n0 + (idx >> 8)) * Dd + (idx & 255)];
  __syncthreads();
  float zz[4] = {0.f, 0.f, 0.f, 0.f};
  for (int d = 0; d < Dd; ++d){
    float kv = kern[(size_t)d * Uu + t];
    #pragma unroll
    for (int r = 0; r < 4; ++r) zz[r] = fmaf(fS[r][d], kv, zz[r]);
  }
  #pragma unroll
  for (int r = 0; r < 4; ++r){
    float v = waveSum(zz[r] * zz[r]);
    if ((t & 63) == 0) red[t >> 6][r] = v;
  }
  __syncthreads();
  #pragma unroll
  for (int r = 0; r < 4; ++r){
    float ns  = red[0][r] + red[1][r];
    float nrm = fmaxf(sqrtf(ns), 1e-15f);
    float th  = tanhf(nrm);
    float xv  = zz[r] * (th / nrm);
    short hb  = f2bf(xv);
    x_hi[(size_t)(n0 + r) * Uu + t] = hb;
    xT_hi[(size_t)t * Nn + (n0 + r)] = hb;
    if (t == 0) x2[n0 + r] = th * th;
  }
}

// b = expmap0(bias); bb[0..127] = b, bb[128] = ||b||^2
__global__ __launch_bounds__(128) void k_bias(const float* __restrict__ bias,
                                              float* __restrict__ bb){
  const int t = threadIdx.x;
  __shared__ float red[2];
  float bv = bias[t];
  float v = waveSum(bv * bv);
  if ((t & 63) == 0) red[t >> 6] = v;
  __syncthreads();
  float n2  = red[0] + red[1];
  float nrm = fmaxf(sqrtf(n2), 1e-15f);
  float th  = tanhf(nrm);
  bb[t] = bv * th / nrm;
  if (t == 0) bb[Uu] = th * th;
}

// fused MFMA flash: S = QK^T (bf16 mfma) -> poincare dist -> masked online softmax -> O += P V (bf16 mfma)
__global__ __launch_bounds__(256) void k_attn(const int* __restrict__ adj,
                                              const short* __restrict__ xh,
                                              const short* __restrict__ xth,
                                              const float* __restrict__ x2g,
                                              const float* __restrict__ bb,
                                              float* __restrict__ out){
  const int t    = threadIdx.x;
  const int lane = t & 63;
  const int wid  = t >> 6;
  const int i0   = blockIdx.x * MI;
  const int l15  = lane & 15;
  const int q4   = lane >> 4;          // 0..3
  const int koff = q4 * 8;             // k offset inside a 32-wide k-block

  __shared__ short qS[MI * Uu];        // 4 KB   Q rows (bf16)
  __shared__ short kS[NJ * Uu];        // 16 KB  K tile rows (bf16)
  __shared__ short vS[Uu * NJ];        // 16 KB  V^T tile ([u][j], bf16)
  __shared__ short pS[MI * PSTR];      // 2.25KB P tile (A-layout source)
  __shared__ float x2jS[NJ];
  __shared__ float x2iS[MI], mS[MI], lSm[MI], alS[MI];
  __shared__ float wrm[4][MI], wrl[4][MI];
  __shared__ float bS[Uu + 1];
  __shared__ float accS[MI * Uu];      // 8 KB   epilogue

  // stage Q (4 KB contiguous)
  ((int4*)qS)[t] = ((const int4*)(xh + (size_t)i0 * Uu))[t];
  if (t < MI){ x2iS[t] = x2g[i0 + t]; mS[t] = -INFINITY; lSm[t] = 0.f; }
  if (t < Uu + 1) bS[t] = bb[t];
  __syncthreads();

  // Q A-fragments live in registers for the whole kernel
  s16x8 qf[4];
  #pragma unroll
  for (int kk = 0; kk < 4; ++kk)
    qf[kk] = *(const s16x8*)(qS + l15 * Uu + kk * 32 + koff);

  f32x4 oacc0 = {0.f, 0.f, 0.f, 0.f};
  f32x4 oacc1 = {0.f, 0.f, 0.f, 0.f};

  for (int j0 = 0; j0 < Nn; j0 += NJ){
    // ---- stage K tile (16 KB contiguous) + V^T tile ----
    {
      const int4* ks = (const int4*)(xh + (size_t)j0 * Uu);
      int4* kd = (int4*)kS;
      #pragma unroll
      for (int c = 0; c < 4; ++c) kd[t + 256 * c] = ks[t + 256 * c];
      int4* vd = (int4*)vS;
      #pragma unroll
      for (int c = 0; c < 4; ++c){
        int g = t + 256 * c;             // 16B granule: row = g>>3, col16 = g&7
        vd[g] = *(const int4*)(xth + (size_t)(g >> 3) * Nn + j0 + (g & 7) * 8);
      }
      if (t < NJ) x2jS[t] = x2g[j0 + t];
    }
    __syncthreads();                                    // A

    // ---- S = Q K^T : one 16x16 tile per wave ----
    f32x4 s = {0.f, 0.f, 0.f, 0.f};
    {
      const short* kb = kS + (wid * 16 + l15) * Uu + koff;
      #pragma unroll
      for (int kk = 0; kk < 4; ++kk){
        s16x8 bf = *(const s16x8*)(kb + kk * 32);
        s = MFMA16(qf[kk], bf, s);
      }
    }

    // ---- closed-form hyperbolic distance + adjacency mask (C layout: col=l15, row=q4*4+r) ----
    const int jl = wid * 16 + l15;
    const int jg = j0 + jl;
    const float x2j = x2jS[jl];
    float sv[4];
    #pragma unroll
    for (int r = 0; r < 4; ++r){
      const int row  = q4 * 4 + r;
      const float x2i = x2iS[row];
      const float xy  = s[r];
      const float Bv  = 1.f - x2i;
      const float Aa  = fmaf(-2.f, xy, 1.f + x2j);
      const float num = fmaf(Aa * Aa, x2i, fmaf(-2.f * Aa * Bv, xy, Bv * Bv * x2j));
      const float den = fmaf(x2i, x2j, fmaf(-2.f, xy, 1.f));
      const float sq  = sqrtf(fmaxf(num, 0.f));
      const float mn  = fminf(sq * __builtin_amdgcn_rcpf(fmaxf(den, 1e-15f)), 1.f - 1e-7f);
      const float dist = __logf((1.f + mn) * __builtin_amdgcn_rcpf(1.f - mn)); // 2*artanh
      const int av = adj[(size_t)(i0 + row) * Nn + jg];
      const bool keep = (av != 0) && (dist != 0.f) && (jg != i0 + row);
      sv[r] = keep ? dist : NEG_MIN;
      float v = sv[r];
      v = fmaxf(v, __shfl_xor(v, 1)); v = fmaxf(v, __shfl_xor(v, 2));
      v = fmaxf(v, __shfl_xor(v, 4)); v = fmaxf(v, __shfl_xor(v, 8));
      if (l15 == 0) wrm[wid][row] = v;
    }
    __syncthreads();                                    // B
    if (t < MI){
      float mt  = fmaxf(fmaxf(wrm[0][t], wrm[1][t]), fmaxf(wrm[2][t], wrm[3][t]));
      float mo  = mS[t];
      float mnw = fmaxf(mo, mt);
      alS[t] = __expf(mo - mnw);
      mS[t]  = mnw;
    }
    __syncthreads();                                    // C

    // ---- p = exp(s - m); write P (bf16, A-source layout); row-sum; rescale O acc ----
    #pragma unroll
    for (int r = 0; r < 4; ++r){
      const int row = q4 * 4 + r;
      float p = __expf(sv[r] - mS[row]);
      pS[row * PSTR + jl] = f2bf(p);
      float v = p;
      v += __shfl_xor(v, 1); v += __shfl_xor(v, 2);
      v += __shfl_xor(v, 4); v += __shfl_xor(v, 8);
      if (l15 == 0) wrl[wid][row] = v;
      const float al = alS[row];
      oacc0[r] *= al;
      oacc1[r] *= al;
    }
    __syncthreads();                                    // D
    if (t < MI)
      lSm[t] = lSm[t] * alS[t] + (wrl[0][t] + wrl[1][t] + wrl[2][t] + wrl[3][t]);

    // ---- O += P V  (wave owns u-chunks wid*32 and wid*32+16) ----
    {
      s16x8 pa0 = *(const s16x8*)(pS + l15 * PSTR + koff);
      s16x8 pa1 = *(const s16x8*)(pS + l15 * PSTR + 32 + koff);
      const short* vb0 = vS + (wid * 32 + l15) * NJ + koff;
      const short* vb1 = vS + (wid * 32 + 16 + l15) * NJ + koff;
      s16x8 b;
      b = *(const s16x8*)(vb0);       oacc0 = MFMA16(pa0, b, oacc0);
      b = *(const s16x8*)(vb0 + 32);  oacc0 = MFMA16(pa1, b, oacc0);
      b = *(const s16x8*)(vb1);       oacc1 = MFMA16(pa0, b, oacc1);
      b = *(const s16x8*)(vb1 + 32);  oacc1 = MFMA16(pa1, b, oacc1);
    }
    __syncthreads();                                    // E
  }

  // ---- park accumulators, then barrier-free per-row epilogue ----
  #pragma unroll
  for (int r = 0; r < 4; ++r){
    const int row = q4 * 4 + r;
    accS[row * Uu + wid * 32 + l15]      = oacc0[r];
    accS[row * Uu + wid * 32 + 16 + l15] = oacc1[r];
  }
  __syncthreads();

  const int er = t >> 4;               // row 0..15
  const int ec = t & 15;               // 16 threads per row, 8 u each
  const float linv = __builtin_amdgcn_rcpf(lSm[er]);
  float mx[8]; float s2 = 0.f;
  #pragma unroll
  for (int k = 0; k < 8; ++k){
    float v = accS[er * Uu + ec + 16 * k] * linv;
    mx[k] = v; s2 = fmaf(v, v, s2);
  }
  s2 += __shfl_xor(s2, 1); s2 += __shfl_xor(s2, 2);
  s2 += __shfl_xor(s2, 4); s2 += __shfl_xor(s2, 8);
  const float mx_n = fmaxf(sqrtf(s2), 1e-15f);
  const float x_n  = fmaxf(sqrtf(x2iS[er]), 1e-15f);
  const float xcl  = fminf(x_n, 1.f - 1e-7f);
  const float art  = 0.5f * __logf((1.f + xcl) / (1.f - xcl));
  const float th   = tanhf(mx_n / x_n * art);
  const float rmn  = th / mx_n;
  float o[8]; float ob = 0.f;
  #pragma unroll
  for (int k = 0; k < 8; ++k){
    o[k] = mx[k] * rmn;
    ob = fmaf(o[k], bS[ec + 16 * k], ob);
  }
  ob += __shfl_xor(ob, 1); ob += __shfl_xor(ob, 2);
  ob += __shfl_xor(ob, 4); ob += __shfl_xor(ob, 8);
  const float o2   = th * th;          // == sum(o^2) analytically
  const float b2   = bS[Uu];
  const float cnum = 1.f + 2.f * ob + b2;
  const float cden = fmaf(o2, b2, 1.f + 2.f * ob);
  const float rden = __builtin_amdgcn_rcpf(fmaxf(cden, 1e-15f));
  const float co   = 1.f - o2;
  #pragma unroll
  for (int k = 0; k < 8; ++k)
    out[(size_t)(i0 + er) * Uu + ec + 16 * k] = (cnum * o[k] + co * bS[ec + 16 * k]) * rden;
}

extern "C" void kernel_launch(void* const* d_in, const int* in_sizes, int n_in,
                              void* d_out, int out_size, void* d_ws, size_t ws_size,
                              hipStream_t stream){
  (void)in_sizes; (void)n_in; (void)out_size; (void)ws_size;
  const float* feat = (const float*)d_in[0];
  const int*   adj  = (const int*)d_in[1];
  const float* kern = (const float*)d_in[2];
  const float* bias = (const float*)d_in[3];

  short* xh  = (short*)d_ws;                       // [N][U] bf16
  short* xth = xh + (size_t)Nn * Uu;               // [U][N] bf16
  float* x2  = (float*)(xth + (size_t)Nn * Uu);    // [N]
  float* bbw = x2 + Nn;                            // [U+1]

  k_prep<<<Nn / 4, 128, 0, stream>>>(feat, kern, xh, xth, x2);
  k_bias<<<1, 128, 0, stream>>>(bias, bbw);
  k_attn<<<Nn / MI, 256, 0, stream>>>(adj, xh, xth, x2, bbw, (float*)d_out);
}

// Round 4
// 709.587 us; speedup vs baseline: 2.2133x; 1.3020x over previous
//
#include <hip/hip_runtime.h>
#include <hip/hip_bf16.h>
#include <math.h>

#define Nn 8192
#define Dd 256
#define Uu 128
#define MI 16

typedef __attribute__((ext_vector_type(4))) float f32x4;
typedef __attribute__((ext_vector_type(8))) short s16x8;
typedef __attribute__((ext_vector_type(4))) short s16x4;

#define MFMA_K32(a, b, c) __builtin_amdgcn_mfma_f32_16x16x32_bf16((a), (b), (c), 0, 0, 0)

#if __has_builtin(__builtin_amdgcn_mfma_f32_16x16x16bf16_1k)
#define MFMA_K16(a, b, c) __builtin_amdgcn_mfma_f32_16x16x16bf16_1k((a), (b), (c), 0, 0, 0)
#elif __has_builtin(__builtin_amdgcn_mfma_f32_16x16x16_bf16)
#define MFMA_K16(a, b, c) __builtin_amdgcn_mfma_f32_16x16x16_bf16((a), (b), (c), 0, 0, 0)
#else
static __device__ __forceinline__ f32x4 mfma_k16_asm(s16x4 a, s16x4 b, f32x4 c){
  asm volatile("v_mfma_f32_16x16x16_bf16 %0, %1, %2, %0" : "+v"(c) : "v"(a), "v"(b));
  return c;
}
#define MFMA_K16(a, b, c) mfma_k16_asm((a), (b), (c))
#endif

__device__ __forceinline__ short f2bf(float f){
  unsigned int u = __float_as_uint(f);
  u += 0x7fffu + ((u >> 16) & 1u);           // RNE
  return (short)(u >> 16);
}

__device__ __forceinline__ float waveSum(float v){
  #pragma unroll
  for (int off = 32; off >= 1; off >>= 1) v += __shfl_xor(v, off);
  return v;
}

// x = expmap0(features @ kernel) -> xh (bf16 [N][U]), xth (bf16 [U][N]), x2 = tanh(|z|)^2
__global__ __launch_bounds__(128) void k_prep(const float* __restrict__ feat,
                                              const float* __restrict__ kern,
                                              short* __restrict__ xh,
                                              short* __restrict__ xth,
                                              float* __restrict__ x2){
  const int t = threadIdx.x;                  // == u
  const int n0 = blockIdx.x * 16;
  __shared__ float fS[16][Dd];
  __shared__ float red[2][16];
  for (int idx = t; idx < 16 * Dd; idx += 128)
    fS[idx >> 8][idx & 255] = feat[(size_t)(n0 + (idx >> 8)) * Dd + (idx & 255)];
  __syncthreads();
  float zz[16];
  #pragma unroll
  for (int r = 0; r < 16; ++r) zz[r] = 0.f;
  for (int d = 0; d < Dd; ++d){
    const float kv = kern[(size_t)d * Uu + t];
    #pragma unroll
    for (int r = 0; r < 16; ++r) zz[r] = fmaf(fS[r][d], kv, zz[r]);
  }
  #pragma unroll
  for (int r = 0; r < 16; ++r){
    float v = waveSum(zz[r] * zz[r]);
    if ((t & 63) == 0) red[t >> 6][r] = v;
  }
  __syncthreads();
  short hv[16];
  #pragma unroll
  for (int r = 0; r < 16; ++r){
    const float ns  = red[0][r] + red[1][r];
    const float nrm = fmaxf(sqrtf(ns), 1e-15f);
    const float th  = tanhf(nrm);
    const float xv  = zz[r] * (th / nrm);
    hv[r] = f2bf(xv);
    xh[(size_t)(n0 + r) * Uu + t] = hv[r];
  }
  s16x8 p0, p1;
  #pragma unroll
  for (int r = 0; r < 8; ++r){ p0[r] = hv[r]; p1[r] = hv[r + 8]; }
  *(s16x8*)(xth + (size_t)t * Nn + n0)     = p0;
  *(s16x8*)(xth + (size_t)t * Nn + n0 + 8) = p1;
  if (t < 16){
    const float ns  = red[0][t] + red[1][t];
    const float nrm = fmaxf(sqrtf(ns), 1e-15f);
    const float th  = tanhf(nrm);
    x2[n0 + t] = th * th;
  }
}

// b = expmap0(bias); bb[0..127] = b, bb[128] = ||b||^2
__global__ __launch_bounds__(128) void k_bias(const float* __restrict__ bias,
                                              float* __restrict__ bb){
  const int t = threadIdx.x;
  __shared__ float red[2];
  float bv = bias[t];
  float v = waveSum(bv * bv);
  if ((t & 63) == 0) red[t >> 6] = v;
  __syncthreads();
  float n2  = red[0] + red[1];
  float nrm = fmaxf(sqrtf(n2), 1e-15f);
  float th  = tanhf(nrm);
  bb[t] = bv * th / nrm;
  if (t == 0) bb[Uu] = th * th;
}

// Barrier-free flash: per wave, S^T = K.Q^T (K=32 mfma) -> dist -> p=exp(dist) (shift 0)
// -> P^T C-layout == B-frag of K=16 mfma -> O^T += V^T.P^T. Combine 4 waves at the end.
__global__ __launch_bounds__(256) void k_attn(const int* __restrict__ adj,
                                              const short* __restrict__ xh,
                                              const short* __restrict__ xth,
                                              const float* __restrict__ x2g,
                                              const float* __restrict__ bb,
                                              float* __restrict__ out){
  const int t    = threadIdx.x;
  const int lane = t & 63;
  const int wid  = t >> 6;
  const int l15  = lane & 15;
  const int q4   = lane >> 4;
  const int i0   = blockIdx.x * MI;
  const int jbase = wid * 16;                 // wave's slice of each 64-j window
  const int irow  = i0 + l15;                 // this lane's i (column of S^T)

  __shared__ float oS[4][Uu][17];             // 34 KB  per-wave O^T partials
  __shared__ float lS[4][16];

  // Q B-frags (K=32): lane n=l15 -> Q row i0+l15, k = kk*32 + q4*8 + ii
  s16x8 qf[4];
  {
    const short* qp = xh + (size_t)irow * Uu + q4 * 8;
    #pragma unroll
    for (int kk = 0; kk < 4; ++kk) qf[kk] = *(const s16x8*)(qp + kk * 32);
  }
  const float x2i = x2g[irow];
  const float Bv  = 1.f - x2i;

  f32x4 oac[8];
  #pragma unroll
  for (int c = 0; c < 8; ++c) oac[c] = (f32x4){0.f, 0.f, 0.f, 0.f};
  float lacc = 0.f;

#define LOADS(JW, KF, AV, XJ, VF) do{                                          \
    const short* kp_ = xh + (size_t)((JW) + l15) * Uu + q4 * 8;                \
    KF[0] = *(const s16x8*)(kp_);                                              \
    KF[1] = *(const s16x8*)(kp_ + 32);                                         \
    KF[2] = *(const s16x8*)(kp_ + 64);                                         \
    KF[3] = *(const s16x8*)(kp_ + 96);                                         \
    AV = *(const int4*)(adj + (size_t)irow * Nn + (JW) + q4 * 4);              \
    XJ = *(const f32x4*)(x2g + (JW) + q4 * 4);                                 \
    const short* vp_ = xth + (size_t)l15 * Nn + (JW) + q4 * 4;                 \
    _Pragma("unroll")                                                          \
    for (int c_ = 0; c_ < 8; ++c_)                                             \
      VF[c_] = *(const s16x4*)(vp_ + (size_t)c_ * 16 * Nn);                    \
  }while(0)

#define COMPUTE(KF, AV, XJ, VF, JW) do{                                        \
    f32x4 s_ = (f32x4){0.f, 0.f, 0.f, 0.f};                                    \
    s_ = MFMA_K32(KF[0], qf[0], s_);                                           \
    s_ = MFMA_K32(KF[1], qf[1], s_);                                           \
    s_ = MFMA_K32(KF[2], qf[2], s_);                                           \
    s_ = MFMA_K32(KF[3], qf[3], s_);                                           \
    const int aarr_[4] = {AV.x, AV.y, AV.z, AV.w};                             \
    s16x4 pb_;                                                                 \
    _Pragma("unroll")                                                          \
    for (int r_ = 0; r_ < 4; ++r_){                                            \
      const int   jgl_ = (JW) + q4 * 4 + r_;                                   \
      const float xy_  = s_[r_];                                               \
      const float x2j_ = XJ[r_];                                               \
      const float Aa_  = fmaf(-2.f, xy_, 1.f + x2j_);                          \
      const float num_ = fmaf(Aa_ * Aa_, x2i,                                  \
                          fmaf(-2.f * Aa_ * Bv, xy_, Bv * Bv * x2j_));         \
      const float den_ = fmaf(x2i, x2j_, fmaf(-2.f, xy_, 1.f));                \
      const float mn_  = fminf(sqrtf(fmaxf(num_, 0.f)) *                       \
                   __builtin_amdgcn_rcpf(fmaxf(den_, 1e-15f)), 1.f - 1e-7f);   \
      const float dist_ = __logf((1.f + mn_) *                                 \
                   __builtin_amdgcn_rcpf(1.f - mn_));                          \
      const bool  keep_ = (aarr_[r_] != 0) && (dist_ != 0.f) && (jgl_ != irow);\
      const float p_ = keep_ ? __expf(dist_) : 0.f;                            \
      lacc += p_;                                                              \
      pb_[r_] = f2bf(p_);                                                      \
    }                                                                          \
    oac[0] = MFMA_K16(VF[0], pb_, oac[0]);                                     \
    oac[1] = MFMA_K16(VF[1], pb_, oac[1]);                                     \
    oac[2] = MFMA_K16(VF[2], pb_, oac[2]);                                     \
    oac[3] = MFMA_K16(VF[3], pb_, oac[3]);                                     \
    oac[4] = MFMA_K16(VF[4], pb_, oac[4]);                                     \
    oac[5] = MFMA_K16(VF[5], pb_, oac[5]);                                     \
    oac[6] = MFMA_K16(VF[6], pb_, oac[6]);                                     \
    oac[7] = MFMA_K16(VF[7], pb_, oac[7]);                                     \
  }while(0)

  s16x8 kfA[4]; int4 avA; f32x4 xjA; s16x4 vfA[8];
  s16x8 kfB[4]; int4 avB; f32x4 xjB; s16x4 vfB[8];
  LOADS(jbase, kfA, avA, xjA, vfA);
  for (int j0 = 0; j0 < Nn; j0 += 128){
    LOADS(j0 + 64 + jbase, kfB, avB, xjB, vfB);
    COMPUTE(kfA, avA, xjA, vfA, j0 + jbase);
    const int jn = ((j0 + 128) & (Nn - 1)) + jbase;
    LOADS(jn, kfA, avA, xjA, vfA);
    COMPUTE(kfB, avB, xjB, vfB, j0 + 64 + jbase);
  }
#undef LOADS
#undef COMPUTE

  // combine 4 waves' partial (l, O^T)
  lacc += __shfl_xor(lacc, 16);
  lacc += __shfl_xor(lacc, 32);
  if (lane < 16) lS[wid][lane] = lacc;
  #pragma unroll
  for (int c = 0; c < 8; ++c){
    #pragma unroll
    for (int r = 0; r < 4; ++r)
      oS[wid][c * 16 + q4 * 4 + r][l15] = oac[c][r];
  }
  __syncthreads();

  // epilogue: mobius matvec rescale + mobius bias add (16 threads per row)
  const int er = t >> 4;
  const int ec = t & 15;
  const float l_   = lS[0][er] + lS[1][er] + lS[2][er] + lS[3][er];
  const float linv = 1.f / fmaxf(l_, 1e-30f);
  float mx[8]; float s2 = 0.f;
  #pragma unroll
  for (int k = 0; k < 8; ++k){
    const int u = ec + 16 * k;
    float v = (oS[0][u][er] + oS[1][u][er] + oS[2][u][er] + oS[3][u][er]) * linv;
    mx[k] = v; s2 = fmaf(v, v, s2);
  }
  s2 += __shfl_xor(s2, 1); s2 += __shfl_xor(s2, 2);
  s2 += __shfl_xor(s2, 4); s2 += __shfl_xor(s2, 8);
  const float mx_n = fmaxf(sqrtf(s2), 1e-15f);
  const float x2e  = x2g[i0 + er];
  const float x_n  = fmaxf(sqrtf(x2e), 1e-15f);
  const float xcl  = fminf(x_n, 1.f - 1e-7f);
  const float art  = 0.5f * __logf((1.f + xcl) / (1.f - xcl));
  const float th   = tanhf(mx_n / x_n * art);
  const float rmn  = th / mx_n;
  float o[8], bu[8]; float ob = 0.f;
  #pragma unroll
  for (int k = 0; k < 8; ++k){
    bu[k] = bb[ec + 16 * k];
    o[k]  = mx[k] * rmn;
    ob = fmaf(o[k], bu[k], ob);
  }
  ob += __shfl_xor(ob, 1); ob += __shfl_xor(ob, 2);
  ob += __shfl_xor(ob, 4); ob += __shfl_xor(ob, 8);
  const float o2   = th * th;
  const float b2   = bb[Uu];
  const float cnum = 1.f + 2.f * ob + b2;
  const float cden = fmaf(o2, b2, 1.f + 2.f * ob);
  const float rden = 1.f / fmaxf(cden, 1e-15f);
  const float co   = 1.f - o2;
  #pragma unroll
  for (int k = 0; k < 8; ++k)
    out[(size_t)(i0 + er) * Uu + ec + 16 * k] = (cnum * o[k] + co * bu[k]) * rden;
}

extern "C" void kernel_launch(void* const* d_in, const int* in_sizes, int n_in,
                              void* d_out, int out_size, void* d_ws, size_t ws_size,
                              hipStream_t stream){
  (void)in_sizes; (void)n_in; (void)out_size; (void)ws_size;
  const float* feat = (const float*)d_in[0];
  const int*   adj  = (const int*)d_in[1];
  const float* kern = (const float*)d_in[2];
  const float* bias = (const float*)d_in[3];

  short* xh  = (short*)d_ws;                       // [N][U] bf16
  short* xth = xh + (size_t)Nn * Uu;               // [U][N] bf16
  float* x2  = (float*)(xth + (size_t)Nn * Uu);    // [N]
  float* bbw = x2 + Nn;                            // [U+1]

  k_prep<<<Nn / 16, 128, 0, stream>>>(feat, kern, xh, xth, x2);
  k_bias<<<1, 128, 0, stream>>>(bias, bbw);
  k_attn<<<Nn / MI, 256, 0, stream>>>(adj, xh, xth, x2, bbw, (float*)d_out);
}